// Round 1
// baseline (256.663 us; speedup 1.0000x reference)
//
#include <hip/hip_runtime.h>
#include <cstdint>
#include <climits>

#define BS 32
#define K 50000
#define NGT 32

// float -> order-preserving uint32 (ascending)
__device__ __forceinline__ unsigned f2key(float f) {
    unsigned b = __float_as_uint(f);
    return (b & 0x80000000u) ? ~b : (b | 0x80000000u);
}
#define KEY_NEG1 0x407FFFFFu  // f2key(-1.0f)

// ---------------- Kernel A: match, loc_t, loss key, pos count ----------------
__global__ __launch_bounds__(256) void kA(const float* __restrict__ conf,
                                          const float* __restrict__ gt,
                                          const float* __restrict__ priors,
                                          float* __restrict__ loc_t,
                                          unsigned* __restrict__ keys,
                                          int* __restrict__ numpos) {
    const int b = blockIdx.y;
    const int k = blockIdx.x * 256 + threadIdx.x;

    __shared__ float gs[NGT * 5];
    __shared__ int gv[NGT];
    if (threadIdx.x < NGT * 5) gs[threadIdx.x] = gt[b * NGT * 5 + threadIdx.x];
    __syncthreads();
    if (threadIdx.x < NGT) {
        const float* g = &gs[threadIdx.x * 5];
        gv[threadIdx.x] = !(g[0] == 0.f && g[1] == 0.f && g[2] == 0.f &&
                            g[3] == 0.f && g[4] == 0.f);
    }
    __syncthreads();
    if (k >= K) return;

    const size_t pidx = (size_t)b * K + k;
    const float* p = priors + pidx * 5;
    const float px = p[0], py = p[1], pw = p[2], ph = p[3], pa = p[4];

    float sx = 0.f, sy = 0.f, sw = 0.f, sh = 0.f, sa = 0.f;
    int cnt = 0;
#pragma unroll
    for (int n = 0; n < NGT; n++) {
        if (!gv[n]) continue;
        const float gx = gs[n * 5], gy = gs[n * 5 + 1], ga = gs[n * 5 + 4];
        if (fabsf(px - gx) <= 16.f && fabsf(py - gy) <= 16.f &&
            fabsf(pa - ga) <= 15.f) {
            cnt++;
            sx += gx; sy += gy; sw += gs[n * 5 + 2]; sh += gs[n * 5 + 3]; sa += ga;
        }
    }

    float lx = sx + 1e-14f, ly = sy + 1e-14f, lw = sw + 1e-14f,
          lh = sh + 1e-14f, la = sa + 1e-14f;
    if (cnt > 0) {
        const float c = (float)cnt;
        lx /= c; ly /= c; lw /= c; lh /= c; la /= c;
    }
    float* o = loc_t + pidx * 5;
    o[0] = ((lx - px) / pw) / 0.1f;
    o[1] = ((ly - py) / ph) / 0.1f;
    o[2] = logf(lw / pw) / 0.2f;
    o[3] = logf(lh / ph) / 0.2f;
    o[4] = (la - pa) / 0.1f;

    // hard-negative-mining loss (label = cnt>0; gathered = c[label])
    const float c0 = conf[pidx * 2], c1 = conf[pidx * 2 + 1];
    const float m = fmaxf(c0, c1);
    const float lse = m + logf(expf(c0 - m) + expf(c1 - m));
    const float loss = (cnt > 0) ? -1.0f : (lse - c0);
    keys[pidx] = f2key(loss);
    if (cnt > 0) atomicAdd(&numpos[b], 1);
}

// ------------- Kernel B: per-row radix select (num_neg-th largest) -----------
__global__ __launch_bounds__(1024) void kB(const unsigned* __restrict__ keys,
                                           const int* __restrict__ numpos,
                                           unsigned* __restrict__ thresh,
                                           int* __restrict__ budget,
                                           float* __restrict__ tie_region) {
    const int row = blockIdx.x;
    const int tid = threadIdx.x;
    const long long want0 = 3LL * (long long)numpos[row];
    if (want0 <= 0) {  // uniform branch: no negatives selected
        if (tid == 0) { thresh[row] = 0xFFFFFFFFu; budget[row] = 0; }
        return;
    }
    const int want_init = (want0 > K) ? K : (int)want0;

    __shared__ int hist[256];
    __shared__ unsigned s_prefix;
    __shared__ int s_want, s_ceq;
    if (tid == 0) { s_prefix = 0u; s_want = want_init; s_ceq = 0; }
    __syncthreads();

    unsigned pmask = 0u;
    const unsigned* kr = keys + (size_t)row * K;
    for (int shift = 24; shift >= 0; shift -= 8) {
        if (tid < 256) hist[tid] = 0;
        __syncthreads();
        const unsigned prefix = s_prefix;
        for (int i = tid; i < K; i += 1024) {
            const unsigned kk = kr[i];
            if ((kk & pmask) == prefix) atomicAdd(&hist[(kk >> shift) & 255u], 1);
        }
        __syncthreads();
        if (tid == 0) {
            const int w = s_want;
            int cum = 0, chosen = 0, ceq = 0;
            for (int bn = 255; bn >= 0; bn--) {
                const int h = hist[bn];
                if (cum + h >= w) { chosen = bn; ceq = h; break; }
                cum += h;
            }
            s_prefix = prefix | ((unsigned)chosen << shift);
            s_want = w - cum;   // 1..ceq
            s_ceq = ceq;
        }
        __syncthreads();
        pmask |= (0xFFu << shift);
    }

    const unsigned uT = s_prefix;
    const int bud = s_want;
    const int ceq = s_ceq;
    if (tid == 0) {
        thresh[row] = uT;
        budget[row] = (bud >= ceq) ? INT_MAX : bud;  // INT_MAX = take all ties
    }
    if (bud >= ceq) return;  // uniform: common case, no ranking needed

    // Rare path: duplicated threshold value. Assign tie ranks in index order
    // (matches stable argsort tie-break). Ballot-based ordered block scan.
    __shared__ int wsum[16];
    __shared__ int s_run;
    if (tid == 0) s_run = 0;
    __syncthreads();
    int* tiei = (int*)tie_region;
    for (int base = 0; base < K; base += 1024) {
        const int i = base + tid;
        const bool eq = (i < K) && (kr[i] == uT);
        const unsigned long long bal = __ballot(eq);
        const int lane = tid & 63, wid = tid >> 6;
        if (lane == 0) wsum[wid] = __popcll(bal);
        __syncthreads();
        if (tid == 0) {
            int acc = s_run;
            for (int w = 0; w < 16; w++) { const int t = wsum[w]; wsum[w] = acc; acc += t; }
            s_run = acc;
        }
        __syncthreads();
        if (eq) {
            const int rank = wsum[wid] + __popcll(bal & ((1ull << lane) - 1ull));
            tiei[(size_t)row * K + i] = rank;
        }
        __syncthreads();
    }
}

// ---------------- Kernel D1: conf_t (reads tie ranks from own slot) ----------
__global__ __launch_bounds__(256) void kD1(const unsigned* __restrict__ keys,
                                           const unsigned* __restrict__ thresh,
                                           const int* __restrict__ budget,
                                           float* __restrict__ confout) {
    const int idx = blockIdx.x * 256 + threadIdx.x;
    if (idx >= BS * K) return;
    const int b = idx / K;
    const unsigned key = keys[idx];
    const unsigned uT = thresh[b];
    const int bud = budget[b];
    const bool pos = (key == KEY_NEG1);
    bool sel;
    if (key > uT) sel = true;
    else if (key == uT) sel = (bud == INT_MAX) || (((const int*)confout)[idx] < bud);
    else sel = false;
    const bool neg = sel && !pos;
    confout[idx] = pos ? 1.0f : (neg ? 0.0f : -1.0f);
}

// ---------------- Kernel D2: iw / ow -----------------------------------------
__global__ __launch_bounds__(256) void kD2(const float* __restrict__ confv,
                                           const int* __restrict__ numpos,
                                           float* __restrict__ iw,
                                           float* __restrict__ ow) {
    const int idx = blockIdx.x * 256 + threadIdx.x;
    if (idx >= BS * K) return;
    const int b = idx / K;
    const float c = confv[idx];
    const float inv = 1.0f / (float)((numpos[b] * 4) | 1);
    const float iwv = (c == 1.0f) ? 1.0f : 0.0f;
    const float owv = (c >= 0.0f) ? inv : 0.0f;
    const size_t o = (size_t)idx * 5;
#pragma unroll
    for (int j = 0; j < 5; j++) { iw[o + j] = iwv; ow[o + j] = owv; }
}

extern "C" void kernel_launch(void* const* d_in, const int* in_sizes, int n_in,
                              void* d_out, int out_size, void* d_ws, size_t ws_size,
                              hipStream_t stream) {
    const float* conf   = (const float*)d_in[0];  // [32,50000,2]
    const float* gt     = (const float*)d_in[1];  // [32,32,5]
    const float* priors = (const float*)d_in[2];  // [32,50000,5]

    float* out   = (float*)d_out;
    float* loc_t = out;                 // 8,000,000
    float* confo = out + 8000000;       // 1,600,000
    float* iw    = out + 9600000;       // 8,000,000
    float* ow    = out + 17600000;      // 8,000,000

    // keys scratch lives in ow region (only clobbered by kD2, after all reads)
    unsigned* keys = (unsigned*)ow;     // 1.6M uints = 6.4 MB of 32 MB region
    int*      numpos = (int*)d_ws;          // 32 ints
    unsigned* thresh = (unsigned*)d_ws + 32;
    int*      budget = (int*)d_ws + 64;

    hipMemsetAsync(d_ws, 0, 3 * 32 * sizeof(int), stream);

    dim3 gA((K + 255) / 256, BS);
    kA<<<gA, 256, 0, stream>>>(conf, gt, priors, loc_t, keys, numpos);
    kB<<<BS, 1024, 0, stream>>>(keys, numpos, thresh, budget, confo);
    kD1<<<(BS * K + 255) / 256, 256, 0, stream>>>(keys, thresh, budget, confo);
    kD2<<<(BS * K + 255) / 256, 256, 0, stream>>>(confo, numpos, iw, ow);
}